// Round 27
// baseline (137.943 us; speedup 1.0000x reference)
//
#include <hip/hip_runtime.h>
#include <math.h>

constexpr int BATCH = 4;
constexpr int NPTS  = 8192;
constexpr int KSEL  = 16;
constexpr int G     = 16;          // 16x16 cells, ~32 pts/cell
constexpr int NC    = G * G;       // 256 cells
constexpr int TILE_MAX = 832;      // LDS tile capacity incl. sentinel padding
constexpr int TILE_USE = 768;      // stage threshold (3x3 neighborhood, mean ~288)
#define CELL_W (1.0 / 16.0)

// ---- workspace layout (bytes) ----
constexpr size_t WS_HIST  = 0;        // BATCH*NC*4        = 4096
constexpr size_t WS_CURS  = 4096;     // BATCH*NC*4        = 4096
constexpr size_t WS_CSTRT = 8192;     // BATCH*(NC+1)*4    = 4112
constexpr size_t WS_PTS   = 16384;    // BATCH*NPTS*16     = 524288  (x,y,idx,sq)

#define PI_F 3.14159265358979323846f

// Fusion barrier (R17-proven): INLINEASM-defined value the DAGCombiner cannot
// contract into FMA (hipcc backend fuses fadd(fmul,fmul) even with contract(off)).
__device__ __forceinline__ float opaque(float v) { asm("" : "+v"(v)); return v; }

__device__ __forceinline__ int cell_of(float x) {
    int c = (int)(x * 16.0f);
    return c < 0 ? 0 : (c > 15 ? 15 : c);
}

// MACRO (not lambda!) — R25 post-mortem: by-reference lambda capture of bd/bi caused
// address escape -> scratch allocation (VGPR=56, 17.6MB spill WRITE traffic). Macro
// expansion keeps the arrays register-resident (R26: WRITE=2048KB, 254->113us).
#define EVAL_INSERT(PJ) do {                                                  \
    float4 _pj = (PJ);                                                        \
    int _j = __float_as_int(_pj.z);                                           \
    float _px  = opaque(__fmul_rn(xq, _pj.x));                                \
    float _dot = fmaf(yq, _pj.y, _px);                                        \
    float _d2  = __fsub_rn(__fadd_rn(sqq, _pj.w), __fmul_rn(2.0f, _dot));     \
    _d2 = (_j == qorig) ? INFINITY : _d2;                                     \
    bool _lt[KSEL];                                                           \
    _Pragma("unroll")                                                         \
    for (int _k = 0; _k < KSEL; ++_k)                                         \
        _lt[_k] = (_d2 < bd[_k]) || (_d2 == bd[_k] && _j < bi[_k]);           \
    _Pragma("unroll")                                                         \
    for (int _k = KSEL - 1; _k >= 1; --_k) {                                  \
        bd[_k] = _lt[_k-1] ? bd[_k-1] : (_lt[_k] ? _d2 : bd[_k]);             \
        bi[_k] = _lt[_k-1] ? bi[_k-1] : (_lt[_k] ? _j  : bi[_k]);             \
    }                                                                         \
    bd[0] = _lt[0] ? _d2 : bd[0];                                             \
    bi[0] = _lt[0] ? _j  : bi[0];                                             \
} while (0)

// ---------------- Kernel 1: features + encode + histogram (fused) ----------------
__global__ __launch_bounds__(256) void feat_encode_hist_kernel(
    const float* __restrict__ coords, const float* __restrict__ demands,
    const float* __restrict__ capacity, const float* __restrict__ curpos,
    const float* __restrict__ Wa,  const float* __restrict__ ba,
    const float* __restrict__ W1,  const float* __restrict__ b1,
    const float* __restrict__ W2,  const float* __restrict__ b2,
    float* __restrict__ out_psi, float* __restrict__ out_feat,
    int* __restrict__ hist)
{
    int gid = blockIdx.x * blockDim.x + threadIdx.x;
    if (gid >= BATCH * NPTS) return;
    int b = gid >> 13;

    float2 c   = ((const float2*)coords)[gid];
    float2 dep = ((const float2*)coords)[(size_t)b * NPTS];
    float2 cn  = ((const float2*)curpos)[b];

    atomicAdd(&hist[b * NC + cell_of(c.y) * G + cell_of(c.x)], 1);

    float relx = c.x - dep.x, rely = c.y - dep.y;
    float dist_depot = sqrtf(relx * relx + rely * rely);
    float angle = atan2f(rely, relx) / PI_F;
    float dem = demands[gid] / capacity[b];
    float dcx = c.x - cn.x, dcy = c.y - cn.y;
    float dist_cur = sqrtf(dcx * dcx + dcy * dcy);

    float f0 = c.x, f1 = c.y, f2 = dem, f3 = dist_depot, f4 = angle, f5 = dist_cur;

    float p0 = ba[0] + f0*Wa[0] + f1*Wa[1] + f2*Wa[2]  + f3*Wa[3]  + f4*Wa[4]  + f5*Wa[5];
    float p1 = ba[1] + f0*Wa[6] + f1*Wa[7] + f2*Wa[8]  + f3*Wa[9]  + f4*Wa[10] + f5*Wa[11];
    float nrm = sqrtf(p0 * p0 + p1 * p1);
    float inv = 1.0f / (nrm + 1e-8f);
    float x = p0 * inv, y = p1 * inv;

    float theta = b2[0];
    #pragma unroll
    for (int j = 0; j < 16; ++j) {
        const float* w = W1 + j * 6;
        float hj = tanhf(b1[j] + f0*w[0] + f1*w[1] + f2*w[2] + f3*w[3] + f4*w[4] + f5*w[5]);
        theta += hj * W2[j];
    }
    float sth, cth;
    sincosf(theta, &sth, &cth);

    ((float2*)out_psi)[gid] = make_float2(cth * x - sth * y, sth * x + cth * y);
    float2* fo = (float2*)out_feat + (size_t)gid * 3;
    fo[0] = make_float2(f0, f1);
    fo[1] = make_float2(f2, f3);
    fo[2] = make_float2(f4, f5);
}

// ---------------- Grid build ----------------
__global__ __launch_bounds__(64) void scan_kernel(const int* __restrict__ hist,
                                                  int* __restrict__ cellStart,
                                                  int* __restrict__ cursor)
{
    int b = blockIdx.x;
    int t = threadIdx.x;                      // 0..63, 4 cells each
    const int4* h4 = (const int4*)(hist + b * NC);
    int4 v = h4[t];
    int s = v.x + v.y + v.z + v.w;

    int inc = s;
    #pragma unroll
    for (int d = 1; d < 64; d <<= 1) {
        int o = __shfl_up(inc, d, 64);
        if (t >= d) inc += o;
    }
    int base = inc - s;
    int e0 = base, e1 = e0 + v.x, e2 = e1 + v.y, e3 = e2 + v.z;
    int* cs = cellStart + b * (NC + 1);
    cs[4*t+0] = e0; cs[4*t+1] = e1; cs[4*t+2] = e2; cs[4*t+3] = e3;
    int* cu = cursor + b * NC;
    cu[4*t+0] = e0; cu[4*t+1] = e1; cu[4*t+2] = e2; cu[4*t+3] = e3;
    if (t == 63) cs[NC] = e3 + v.w;           // = NPTS
}

__global__ __launch_bounds__(256) void scatter_kernel(const float* __restrict__ coords,
                                                      int* __restrict__ cursor,
                                                      float4* __restrict__ pts)
{
    int gid = blockIdx.x * 256 + threadIdx.x;
    if (gid >= BATCH * NPTS) return;
    int b = gid >> 13, n = gid & (NPTS - 1);
    float2 c = ((const float2*)coords)[gid];
    float sx = opaque(__fmul_rn(c.x, c.x));
    float sy = opaque(__fmul_rn(c.y, c.y));
    float sq = __fadd_rn(sx, sy);                 // unfused (a)-sq, verified chain
    int pos = atomicAdd(&cursor[b * NC + cell_of(c.y) * G + cell_of(c.x)], 1);
    pts[(b << 13) + pos] = make_float4(c.x, c.y, __int_as_float(n), sq);
}

// ---------------- Kernel 2: block-per-half-cell 16-NN ----------------
// Chain (== R20-R26 PASSING, bit-exact): sq unfused (scatter), dot=fma(y,yj,round(x*xj)),
// d2 = (sqi+sqj)-2*dot, lex (d2,j) stable-low ties. Algorithm == R26.
// R26 post-mortem: 1024 blocks (4/CU queue) + per-block work variance (cnt x tile, both
// +-40%) -> tail-dominated, Occupancy 19%, VALUBusy 31%. Fix: 2 blocks per cell
// (parity split on qi via blockIdx.z) x 128 threads (16 slots x 8 lanes, matching the
// ~16 queries each half owns) -> 2048 blocks, 2 waves each, 8 blocks/CU queued,
// LDS allows 12 blocks/CU residency. Per-query work identical.
__global__ __launch_bounds__(128) void knn_cell_kernel(
    const int* __restrict__ cellStart, const float4* __restrict__ pts,
    float* __restrict__ out_knn)
{
    const int b    = blockIdx.y;
    const int cell = blockIdx.x;
    const int half = blockIdx.z;                  // 0/1: qi parity
    const int cx = cell & (G - 1), cy = cell >> 4;
    const int* cs = cellStart + b * (NC + 1);
    const float4* pb = pts + ((size_t)b << 13);
    const int qbeg = cs[cell], qend = cs[cell + 1];
    const int cnt = qend - qbeg;
    if (cnt <= half) return;                      // no query with this parity

    __shared__ float4 tile[TILE_MAX];

    const int x0 = max(cx - 1, 0), x1 = min(cx + 1, G - 1);
    int b0 = 0, l0 = 0, b1r = 0, l1r = 0, b2 = 0, l2 = 0;
    if (cy - 1 >= 0)     { b0  = cs[(cy-1)*G + x0]; l0  = cs[(cy-1)*G + x1 + 1] - b0;  }
    {                      b1r = cs[ cy   *G + x0]; l1r = cs[ cy   *G + x1 + 1] - b1r; }
    if (cy + 1 <= G - 1) { b2  = cs[(cy+1)*G + x0]; l2  = cs[(cy+1)*G + x1 + 1] - b2;  }
    const int o1 = l0, o2 = l0 + l1r, total = o2 + l2;
    const int totalPad = (total + 63) & ~63;
    const bool useLds = (total <= TILE_USE);

    if (useLds) {
        for (int i = threadIdx.x; i < l0;  i += 128) tile[i]      = pb[b0  + i];
        for (int i = threadIdx.x; i < l1r; i += 128) tile[o1 + i] = pb[b1r + i];
        for (int i = threadIdx.x; i < l2;  i += 128) tile[o2 + i] = pb[b2  + i];
        for (int i = total + (int)threadIdx.x; i < totalPad; i += 128)
            tile[i] = make_float4(0.0f, 0.0f, __int_as_float(0x7ffffe00), INFINITY);
    }
    __syncthreads();

    const int l8 = threadIdx.x & 7;

    for (int qi = 2 * (threadIdx.x >> 3) + half; qi < cnt; qi += 32) {
        const int p = qbeg + qi;
        float4 me = pb[p];
        const float xq = me.x, yq = me.y, sqq = me.w;
        const int qorig = __float_as_int(me.z);
        const double xqd = (double)xq, yqd = (double)yq;

        float bd[KSEL];
        int   bi[KSEL];
        #pragma unroll
        for (int i = 0; i < KSEL; ++i) { bd[i] = INFINITY; bi[i] = 0x7fffffff; }

        bool done = false;
        int mStart = 0;

        if (useLds) {
            // batch-8 register staging: amortize LDS latency over 8 candidates
            for (int base = 0; base < totalPad; base += 64) {
                float4 cvec[8];
                #pragma unroll
                for (int i = 0; i < 8; ++i) cvec[i] = tile[base + 8 * i + l8];
                #pragma unroll
                for (int i = 0; i < 8; ++i) EVAL_INSERT(cvec[i]);
            }
            float t15 = bd[KSEL-1];
            t15 = fminf(t15, __shfl_xor(t15, 1));
            t15 = fminf(t15, __shfl_xor(t15, 2));
            t15 = fminf(t15, __shfl_xor(t15, 4));
            float t1 = bd[1];
            t1 = fmaxf(t1, __shfl_xor(t1, 1));
            t1 = fmaxf(t1, __shfl_xor(t1, 2));
            t1 = fmaxf(t1, __shfl_xor(t1, 4));
            float ub = fminf(t15, t1);
            double Rl = (cx - 1 > 0)     ? (xqd - (double)(cx - 1) * CELL_W)     : INFINITY;
            double Rr = (cx + 1 < G - 1) ? ((double)(cx + 2) * CELL_W - xqd)     : INFINITY;
            double Rb = (cy - 1 > 0)     ? (yqd - (double)(cy - 1) * CELL_W)     : INFINITY;
            double Rt = (cy + 1 < G - 1) ? ((double)(cy + 2) * CELL_W - yqd)     : INFINITY;
            double R  = fmin(fmin(Rl, Rr), fmin(Rb, Rt)) - 1e-7;
            done = ((double)ub <= R * R - 1e-5);
            mStart = 2;
        }

        // global-memory ring fallback (rare: sparse corners / tile overflow)
        for (int m = mStart; m < G && !done; ++m) {
            int rx0 = max(cx - m, 0), rx1 = min(cx + m, G - 1);
            if (cy - m >= 0) {
                int cb_ = cs[(cy - m) * G + rx0], ce_ = cs[(cy - m) * G + rx1 + 1];
                for (int t = cb_ + l8; t < ce_; t += 8) EVAL_INSERT(pb[t]);
            }
            if (m > 0 && cy + m <= G - 1) {
                int cb_ = cs[(cy + m) * G + rx0], ce_ = cs[(cy + m) * G + rx1 + 1];
                for (int t = cb_ + l8; t < ce_; t += 8) EVAL_INSERT(pb[t]);
            }
            if (m > 0) {
                int yA = max(cy - m + 1, 0), yB = min(cy + m - 1, G - 1);
                if (cx - m >= 0)
                    for (int yy = yA; yy <= yB; ++yy) {
                        int cb_ = cs[yy * G + (cx - m)], ce_ = cs[yy * G + (cx - m) + 1];
                        for (int t = cb_ + l8; t < ce_; t += 8) EVAL_INSERT(pb[t]);
                    }
                if (cx + m <= G - 1)
                    for (int yy = yA; yy <= yB; ++yy) {
                        int cb_ = cs[yy * G + (cx + m)], ce_ = cs[yy * G + (cx + m) + 1];
                        for (int t = cb_ + l8; t < ce_; t += 8) EVAL_INSERT(pb[t]);
                    }
            }
            float t15 = bd[KSEL-1];
            t15 = fminf(t15, __shfl_xor(t15, 1));
            t15 = fminf(t15, __shfl_xor(t15, 2));
            t15 = fminf(t15, __shfl_xor(t15, 4));
            float t1 = bd[1];
            t1 = fmaxf(t1, __shfl_xor(t1, 1));
            t1 = fmaxf(t1, __shfl_xor(t1, 2));
            t1 = fmaxf(t1, __shfl_xor(t1, 4));
            float ub = fminf(t15, t1);
            double Rl = (cx - m > 0)     ? (xqd - (double)(cx - m) * CELL_W)     : INFINITY;
            double Rr = (cx + m < G - 1) ? ((double)(cx + m + 1) * CELL_W - xqd) : INFINITY;
            double Rb = (cy - m > 0)     ? (yqd - (double)(cy - m) * CELL_W)     : INFINITY;
            double Rt = (cy + m < G - 1) ? ((double)(cy + m + 1) * CELL_W - yqd) : INFINITY;
            double R  = fmin(fmin(Rl, Rr), fmin(Rb, Rt)) - 1e-7;
            if ((double)ub <= R * R - 1e-5) done = true;
        }

        // ---- register-only lex-exact 8-list merge: 16x extract-min via butterfly ----
        float v0 = 0.0f, v1 = 0.0f;
        #pragma unroll
        for (int s = 0; s < KSEL; ++s) {
            float hd = bd[0]; int hi = bi[0];
            #pragma unroll
            for (int d = 1; d < 8; d <<= 1) {
                float od = __shfl_xor(hd, d);
                int   oi = __shfl_xor(hi, d);
                bool take = (od < hd) || (od == hd && oi < hi);
                hd = take ? od : hd;
                hi = take ? oi : hi;
            }
            if (2 * l8     == s) v0 = (float)hi;
            if (2 * l8 + 1 == s) v1 = (float)hi;
            bool mine = (bd[0] == hd) && (bi[0] == hi);   // (d2,j) unique among real cands
            if (mine) {
                #pragma unroll
                for (int k = 0; k < KSEL - 1; ++k) { bd[k] = bd[k+1]; bi[k] = bi[k+1]; }
                bd[KSEL-1] = INFINITY; bi[KSEL-1] = 0x7fffffff;
            }
        }
        float* o = out_knn + ((size_t)b * NPTS + qorig) * KSEL;
        *(float2*)(o + 2 * l8) = make_float2(v0, v1);     // 8 lanes cover the 64B line
    }
}

// ---------------- launch ----------------
extern "C" void kernel_launch(void* const* d_in, const int* in_sizes, int n_in,
                              void* d_out, int out_size, void* d_ws, size_t ws_size,
                              hipStream_t stream) {
    const float* coords   = (const float*)d_in[0];
    const float* demands  = (const float*)d_in[1];
    const float* capacity = (const float*)d_in[2];
    const float* curpos   = (const float*)d_in[3];
    const float* Wa       = (const float*)d_in[4];
    const float* ba       = (const float*)d_in[5];
    const float* W1       = (const float*)d_in[6];
    const float* b1       = (const float*)d_in[7];
    const float* W2       = (const float*)d_in[8];
    const float* b2       = (const float*)d_in[9];
    // d_in[10] = knn_k (always 16, hardcoded)

    float* out      = (float*)d_out;
    float* out_psi  = out;                    // 4*8192*2  = 65536
    float* out_feat = out + 65536;            // 4*8192*6  = 196608
    float* out_knn  = out + 65536 + 196608;   // 4*8192*16 = 524288

    int*    hist      = (int*)   ((char*)d_ws + WS_HIST);
    int*    cursor    = (int*)   ((char*)d_ws + WS_CURS);
    int*    cellStart = (int*)   ((char*)d_ws + WS_CSTRT);
    float4* pts       = (float4*)((char*)d_ws + WS_PTS);

    hipMemsetAsync(hist, 0, BATCH * NC * sizeof(int), stream);

    feat_encode_hist_kernel<<<dim3((BATCH * NPTS) / 256), dim3(256), 0, stream>>>(
        coords, demands, capacity, curpos, Wa, ba, W1, b1, W2, b2, out_psi, out_feat, hist);

    scan_kernel<<<dim3(BATCH), dim3(64), 0, stream>>>(hist, cellStart, cursor);
    scatter_kernel<<<dim3((BATCH * NPTS) / 256), dim3(256), 0, stream>>>(coords, cursor, pts);

    knn_cell_kernel<<<dim3(NC, BATCH, 2), dim3(128), 0, stream>>>(cellStart, pts, out_knn);
}

// Round 28
// 65.870 us; speedup vs baseline: 2.0942x; 2.0942x over previous
//
#include <hip/hip_runtime.h>
#include <math.h>

constexpr int BATCH = 4;
constexpr int NPTS  = 8192;
constexpr int KSEL  = 16;
constexpr int G     = 24;          // 24x24 cells, ~14 pts/cell; 3x3 tile ~128 pts
constexpr int NC    = G * G;       // 576 cells
constexpr int TILE_MAX = 384;      // LDS tile capacity incl. sentinel padding (mean 128)
constexpr int TILE_USE = 320;      // stage threshold
#define CELL_W (1.0 / 24.0)

// ---- workspace layout (bytes) ----
constexpr size_t WS_HIST  = 0;        // BATCH*NC*4        = 9216
constexpr size_t WS_CURS  = 9216;     // BATCH*NC*4        = 9216
constexpr size_t WS_CSTRT = 18432;    // BATCH*(NC+1)*4    = 9232
constexpr size_t WS_PTS   = 32768;    // BATCH*NPTS*16     = 524288  (x,y,idx,sq)

#define PI_F 3.14159265358979323846f

// Fusion barrier (R17-proven): INLINEASM-defined value the DAGCombiner cannot
// contract into FMA (hipcc backend fuses fadd(fmul,fmul) even with contract(off)).
__device__ __forceinline__ float opaque(float v) { asm("" : "+v"(v)); return v; }

__device__ __forceinline__ int cell_of(float x) {
    int c = (int)(x * 24.0f);
    return c < 0 ? 0 : (c > G - 1 ? G - 1 : c);
}

// Monotone float->u32 map: preserves total order of all values occurring here
// (d2 is never -0.0: fsub of equal operands yields +0.0; never NaN). INF maps to
// 0xFF800000 < init sentinel. Lower index j = smaller key on equal d2 (stable-low).
__device__ __forceinline__ unsigned int fkey(float f) {
    unsigned int b = __float_as_uint(f);
    return b ^ (((unsigned int)(((int)b) >> 31)) | 0x80000000u);
}
__device__ __forceinline__ float unkey(unsigned int u) {
    unsigned int b = u ^ ((u & 0x80000000u) ? 0x80000000u : 0xFFFFFFFFu);
    return __uint_as_float(b);
}

// MACRO (not lambda!) — R25 post-mortem: by-ref lambda capture of the top-16 arrays
// caused scratch spill (17.6MB WRITE). u64-packed keys: lex (d2,j) compare = ONE
// v_cmp_lt_u64; slot update = 4 cndmask. ~90 ops/eval vs ~150 for the float+int form.
#define EVAL_INSERT(PJ) do {                                                  \
    float4 _pj = (PJ);                                                        \
    int _j = __float_as_int(_pj.z);                                           \
    float _px  = opaque(__fmul_rn(xq, _pj.x));                                \
    float _dot = fmaf(yq, _pj.y, _px);                                        \
    float _d2  = __fsub_rn(__fadd_rn(sqq, _pj.w), __fmul_rn(2.0f, _dot));     \
    _d2 = (_j == qorig) ? INFINITY : _d2;                                     \
    unsigned long long _key =                                                 \
        ((unsigned long long)fkey(_d2) << 32) | (unsigned int)_j;             \
    bool _lt[KSEL];                                                           \
    _Pragma("unroll")                                                         \
    for (int _k = 0; _k < KSEL; ++_k) _lt[_k] = _key < bk[_k];                \
    _Pragma("unroll")                                                         \
    for (int _k = KSEL - 1; _k >= 1; --_k)                                    \
        bk[_k] = _lt[_k-1] ? bk[_k-1] : (_lt[_k] ? _key : bk[_k]);            \
    bk[0] = _lt[0] ? _key : bk[0];                                            \
} while (0)

// init key: unpacks to +INF (keeps termination bound conservative), larger than any
// real or sentinel key.
#define INIT_KEY 0xFF800000FFFFFFFFull

// ---------------- Kernel 1: features + encode + histogram (fused) ----------------
__global__ __launch_bounds__(256) void feat_encode_hist_kernel(
    const float* __restrict__ coords, const float* __restrict__ demands,
    const float* __restrict__ capacity, const float* __restrict__ curpos,
    const float* __restrict__ Wa,  const float* __restrict__ ba,
    const float* __restrict__ W1,  const float* __restrict__ b1,
    const float* __restrict__ W2,  const float* __restrict__ b2,
    float* __restrict__ out_psi, float* __restrict__ out_feat,
    int* __restrict__ hist)
{
    int gid = blockIdx.x * blockDim.x + threadIdx.x;
    if (gid >= BATCH * NPTS) return;
    int b = gid >> 13;

    float2 c   = ((const float2*)coords)[gid];
    float2 dep = ((const float2*)coords)[(size_t)b * NPTS];
    float2 cn  = ((const float2*)curpos)[b];

    atomicAdd(&hist[b * NC + cell_of(c.y) * G + cell_of(c.x)], 1);

    float relx = c.x - dep.x, rely = c.y - dep.y;
    float dist_depot = sqrtf(relx * relx + rely * rely);
    float angle = atan2f(rely, relx) / PI_F;
    float dem = demands[gid] / capacity[b];
    float dcx = c.x - cn.x, dcy = c.y - cn.y;
    float dist_cur = sqrtf(dcx * dcx + dcy * dcy);

    float f0 = c.x, f1 = c.y, f2 = dem, f3 = dist_depot, f4 = angle, f5 = dist_cur;

    float p0 = ba[0] + f0*Wa[0] + f1*Wa[1] + f2*Wa[2]  + f3*Wa[3]  + f4*Wa[4]  + f5*Wa[5];
    float p1 = ba[1] + f0*Wa[6] + f1*Wa[7] + f2*Wa[8]  + f3*Wa[9]  + f4*Wa[10] + f5*Wa[11];
    float nrm = sqrtf(p0 * p0 + p1 * p1);
    float inv = 1.0f / (nrm + 1e-8f);
    float x = p0 * inv, y = p1 * inv;

    float theta = b2[0];
    #pragma unroll
    for (int j = 0; j < 16; ++j) {
        const float* w = W1 + j * 6;
        float hj = tanhf(b1[j] + f0*w[0] + f1*w[1] + f2*w[2] + f3*w[3] + f4*w[4] + f5*w[5]);
        theta += hj * W2[j];
    }
    float sth, cth;
    sincosf(theta, &sth, &cth);

    ((float2*)out_psi)[gid] = make_float2(cth * x - sth * y, sth * x + cth * y);
    float2* fo = (float2*)out_feat + (size_t)gid * 3;
    fo[0] = make_float2(f0, f1);
    fo[1] = make_float2(f2, f3);
    fo[2] = make_float2(f4, f5);
}

// ---------------- Grid build: 1 wave per batch, 9 cells per lane ----------------
__global__ __launch_bounds__(64) void scan_kernel(const int* __restrict__ hist,
                                                  int* __restrict__ cellStart,
                                                  int* __restrict__ cursor)
{
    int b = blockIdx.x;
    int t = threadIdx.x;                      // 0..63, cells [9t, 9t+9)
    int h[9];
    int s = 0;
    #pragma unroll
    for (int i = 0; i < 9; ++i) { h[i] = hist[b * NC + t * 9 + i]; s += h[i]; }

    int inc = s;
    #pragma unroll
    for (int d = 1; d < 64; d <<= 1) {
        int o = __shfl_up(inc, d, 64);
        if (t >= d) inc += o;
    }
    int run = inc - s;                        // exclusive prefix
    int* cs = cellStart + b * (NC + 1);
    int* cu = cursor + b * NC;
    #pragma unroll
    for (int i = 0; i < 9; ++i) {
        cs[t * 9 + i] = run;
        cu[t * 9 + i] = run;
        run += h[i];
    }
    if (t == 63) cs[NC] = run;                // = NPTS
}

__global__ __launch_bounds__(256) void scatter_kernel(const float* __restrict__ coords,
                                                      int* __restrict__ cursor,
                                                      float4* __restrict__ pts)
{
    int gid = blockIdx.x * 256 + threadIdx.x;
    if (gid >= BATCH * NPTS) return;
    int b = gid >> 13, n = gid & (NPTS - 1);
    float2 c = ((const float2*)coords)[gid];
    float sx = opaque(__fmul_rn(c.x, c.x));
    float sy = opaque(__fmul_rn(c.y, c.y));
    float sq = __fadd_rn(sx, sy);                 // unfused (a)-sq, verified chain
    int pos = atomicAdd(&cursor[b * NC + cell_of(c.y) * G + cell_of(c.x)], 1);
    pts[(b << 13) + pos] = make_float4(c.x, c.y, __int_as_float(n), sq);
}

// ---------------- Kernel 2: block-per-cell 16-NN, u64 keys, G=24 ----------------
// Chain (== R20-R27 PASSING, bit-exact): sq unfused (scatter), dot=fma(y,yj,round(x*xj)),
// d2 = (sqi+sqj)-2*dot, lex (d2,j) stable-low ties via u64 key order.
// G=24 (work model from R22/R23/R26): 3x3 tile ~128 cands (vs 288 @G=16), R>=1/24 ->
// R^2=1.74e-3 >> r16^2~6.3e-4 so m=1 terminates ~always. u64 keys cut the insert
// network ~1.65x. Bound min(min_l bd15, max_l bd1), butterfly merge, ring fallback
// semantics identical.
__global__ __launch_bounds__(128) void knn_cell_kernel(
    const int* __restrict__ cellStart, const float4* __restrict__ pts,
    float* __restrict__ out_knn)
{
    const int b    = blockIdx.y;
    const int cell = blockIdx.x;
    const int cx = cell % G, cy = cell / G;
    const int* cs = cellStart + b * (NC + 1);
    const float4* pb = pts + ((size_t)b << 13);
    const int qbeg = cs[cell], qend = cs[cell + 1];
    const int cnt = qend - qbeg;
    if (cnt == 0) return;

    __shared__ float4 tile[TILE_MAX];

    const int x0 = max(cx - 1, 0), x1 = min(cx + 1, G - 1);
    int b0 = 0, l0 = 0, b1r = 0, l1r = 0, b2 = 0, l2 = 0;
    if (cy - 1 >= 0)     { b0  = cs[(cy-1)*G + x0]; l0  = cs[(cy-1)*G + x1 + 1] - b0;  }
    {                      b1r = cs[ cy   *G + x0]; l1r = cs[ cy   *G + x1 + 1] - b1r; }
    if (cy + 1 <= G - 1) { b2  = cs[(cy+1)*G + x0]; l2  = cs[(cy+1)*G + x1 + 1] - b2;  }
    const int o1 = l0, o2 = l0 + l1r, total = o2 + l2;
    const int totalPad = (total + 63) & ~63;
    const bool useLds = (total <= TILE_USE);

    if (useLds) {
        for (int i = threadIdx.x; i < l0;  i += 128) tile[i]      = pb[b0  + i];
        for (int i = threadIdx.x; i < l1r; i += 128) tile[o1 + i] = pb[b1r + i];
        for (int i = threadIdx.x; i < l2;  i += 128) tile[o2 + i] = pb[b2  + i];
        for (int i = total + (int)threadIdx.x; i < totalPad; i += 128)
            tile[i] = make_float4(0.0f, 0.0f, __int_as_float(0x7ffffe00), INFINITY);
    }
    __syncthreads();

    const int l8 = threadIdx.x & 7;

    for (int qi = threadIdx.x >> 3; qi < cnt; qi += 16) {
        const int p = qbeg + qi;
        float4 me = pb[p];
        const float xq = me.x, yq = me.y, sqq = me.w;
        const int qorig = __float_as_int(me.z);
        const double xqd = (double)xq, yqd = (double)yq;

        unsigned long long bk[KSEL];
        #pragma unroll
        for (int i = 0; i < KSEL; ++i) bk[i] = INIT_KEY;

        bool done = false;
        int mStart = 0;

        if (useLds) {
            // batch-8 register staging: amortize LDS latency over 8 candidates
            for (int base = 0; base < totalPad; base += 64) {
                float4 cvec[8];
                #pragma unroll
                for (int i = 0; i < 8; ++i) cvec[i] = tile[base + 8 * i + l8];
                #pragma unroll
                for (int i = 0; i < 8; ++i) EVAL_INSERT(cvec[i]);
            }
            float t15 = unkey((unsigned int)(bk[KSEL-1] >> 32));
            t15 = fminf(t15, __shfl_xor(t15, 1));
            t15 = fminf(t15, __shfl_xor(t15, 2));
            t15 = fminf(t15, __shfl_xor(t15, 4));
            float t1 = unkey((unsigned int)(bk[1] >> 32));
            t1 = fmaxf(t1, __shfl_xor(t1, 1));
            t1 = fmaxf(t1, __shfl_xor(t1, 2));
            t1 = fmaxf(t1, __shfl_xor(t1, 4));
            float ub = fminf(t15, t1);
            double Rl = (cx - 1 > 0)     ? (xqd - (double)(cx - 1) * CELL_W)     : INFINITY;
            double Rr = (cx + 1 < G - 1) ? ((double)(cx + 2) * CELL_W - xqd)     : INFINITY;
            double Rb = (cy - 1 > 0)     ? (yqd - (double)(cy - 1) * CELL_W)     : INFINITY;
            double Rt = (cy + 1 < G - 1) ? ((double)(cy + 2) * CELL_W - yqd)     : INFINITY;
            double R  = fmin(fmin(Rl, Rr), fmin(Rb, Rt)) - 1e-7;
            done = ((double)ub <= R * R - 1e-5);
            mStart = 2;
        }

        // global-memory ring fallback (rare: edge queries / tile overflow)
        for (int m = mStart; m < G && !done; ++m) {
            int rx0 = max(cx - m, 0), rx1 = min(cx + m, G - 1);
            if (cy - m >= 0) {
                int cb_ = cs[(cy - m) * G + rx0], ce_ = cs[(cy - m) * G + rx1 + 1];
                for (int t = cb_ + l8; t < ce_; t += 8) EVAL_INSERT(pb[t]);
            }
            if (m > 0 && cy + m <= G - 1) {
                int cb_ = cs[(cy + m) * G + rx0], ce_ = cs[(cy + m) * G + rx1 + 1];
                for (int t = cb_ + l8; t < ce_; t += 8) EVAL_INSERT(pb[t]);
            }
            if (m > 0) {
                int yA = max(cy - m + 1, 0), yB = min(cy + m - 1, G - 1);
                if (cx - m >= 0)
                    for (int yy = yA; yy <= yB; ++yy) {
                        int cb_ = cs[yy * G + (cx - m)], ce_ = cs[yy * G + (cx - m) + 1];
                        for (int t = cb_ + l8; t < ce_; t += 8) EVAL_INSERT(pb[t]);
                    }
                if (cx + m <= G - 1)
                    for (int yy = yA; yy <= yB; ++yy) {
                        int cb_ = cs[yy * G + (cx + m)], ce_ = cs[yy * G + (cx + m) + 1];
                        for (int t = cb_ + l8; t < ce_; t += 8) EVAL_INSERT(pb[t]);
                    }
            }
            float t15 = unkey((unsigned int)(bk[KSEL-1] >> 32));
            t15 = fminf(t15, __shfl_xor(t15, 1));
            t15 = fminf(t15, __shfl_xor(t15, 2));
            t15 = fminf(t15, __shfl_xor(t15, 4));
            float t1 = unkey((unsigned int)(bk[1] >> 32));
            t1 = fmaxf(t1, __shfl_xor(t1, 1));
            t1 = fmaxf(t1, __shfl_xor(t1, 2));
            t1 = fmaxf(t1, __shfl_xor(t1, 4));
            float ub = fminf(t15, t1);
            double Rl = (cx - m > 0)     ? (xqd - (double)(cx - m) * CELL_W)     : INFINITY;
            double Rr = (cx + m < G - 1) ? ((double)(cx + m + 1) * CELL_W - xqd) : INFINITY;
            double Rb = (cy - m > 0)     ? (yqd - (double)(cy - m) * CELL_W)     : INFINITY;
            double Rt = (cy + m < G - 1) ? ((double)(cy + m + 1) * CELL_W - yqd) : INFINITY;
            double R  = fmin(fmin(Rl, Rr), fmin(Rb, Rt)) - 1e-7;
            if ((double)ub <= R * R - 1e-5) done = true;
        }

        // ---- register-only lex-exact 8-list merge: 16x extract-min via butterfly ----
        // keys unique among real candidates (j embedded); INF-keyed entries never reach
        // the final 16 when >=16 reals were scanned (guaranteed by termination logic).
        float v0 = 0.0f, v1 = 0.0f;
        #pragma unroll
        for (int s = 0; s < KSEL; ++s) {
            unsigned long long hk = bk[0];
            #pragma unroll
            for (int d = 1; d < 8; d <<= 1) {
                unsigned long long ok = __shfl_xor(hk, d);
                hk = (ok < hk) ? ok : hk;
            }
            int hi = (int)(unsigned int)hk;
            if (2 * l8     == s) v0 = (float)hi;
            if (2 * l8 + 1 == s) v1 = (float)hi;
            bool mine = (bk[0] == hk);
            if (mine) {
                #pragma unroll
                for (int k = 0; k < KSEL - 1; ++k) bk[k] = bk[k+1];
                bk[KSEL-1] = INIT_KEY;
            }
        }
        float* o = out_knn + ((size_t)b * NPTS + qorig) * KSEL;
        *(float2*)(o + 2 * l8) = make_float2(v0, v1);     // 8 lanes cover the 64B line
    }
}

// ---------------- launch ----------------
extern "C" void kernel_launch(void* const* d_in, const int* in_sizes, int n_in,
                              void* d_out, int out_size, void* d_ws, size_t ws_size,
                              hipStream_t stream) {
    const float* coords   = (const float*)d_in[0];
    const float* demands  = (const float*)d_in[1];
    const float* capacity = (const float*)d_in[2];
    const float* curpos   = (const float*)d_in[3];
    const float* Wa       = (const float*)d_in[4];
    const float* ba       = (const float*)d_in[5];
    const float* W1       = (const float*)d_in[6];
    const float* b1       = (const float*)d_in[7];
    const float* W2       = (const float*)d_in[8];
    const float* b2       = (const float*)d_in[9];
    // d_in[10] = knn_k (always 16, hardcoded)

    float* out      = (float*)d_out;
    float* out_psi  = out;                    // 4*8192*2  = 65536
    float* out_feat = out + 65536;            // 4*8192*6  = 196608
    float* out_knn  = out + 65536 + 196608;   // 4*8192*16 = 524288

    int*    hist      = (int*)   ((char*)d_ws + WS_HIST);
    int*    cursor    = (int*)   ((char*)d_ws + WS_CURS);
    int*    cellStart = (int*)   ((char*)d_ws + WS_CSTRT);
    float4* pts       = (float4*)((char*)d_ws + WS_PTS);

    hipMemsetAsync(hist, 0, BATCH * NC * sizeof(int), stream);

    feat_encode_hist_kernel<<<dim3((BATCH * NPTS) / 256), dim3(256), 0, stream>>>(
        coords, demands, capacity, curpos, Wa, ba, W1, b1, W2, b2, out_psi, out_feat, hist);

    scan_kernel<<<dim3(BATCH), dim3(64), 0, stream>>>(hist, cellStart, cursor);
    scatter_kernel<<<dim3((BATCH * NPTS) / 256), dim3(256), 0, stream>>>(coords, cursor, pts);

    knn_cell_kernel<<<dim3(NC, BATCH), dim3(128), 0, stream>>>(cellStart, pts, out_knn);
}